// Round 7
// baseline (241.190 us; speedup 1.0000x reference)
//
#include <hip/hip_runtime.h>
#include <hip/hip_bf16.h>

typedef unsigned short u16;
typedef __attribute__((ext_vector_type(8))) __bf16 bf16x8;
typedef __attribute__((ext_vector_type(4))) float f32x4;
typedef __attribute__((ext_vector_type(4))) unsigned int u32x4;

// Problem dims
#define BB 32
#define LL 512
#define CC 512
#define HH 8
#define DH 64
#define MROWS (BB * LL)        // 16384
#define NQKV  (3 * CC)         // 1536

// workspace layout (bytes)
#define XB_BYTES ((size_t)MROWS * CC * 2)        // 16,777,216  (x bf16; later reused as vT)
#define WC_BYTES ((size_t)NQKV * CC * 2)         //  1,572,864  (wq|wk|wv bf16; dead after gemm -> biasT)
#define QKV_OFF  (XB_BYTES + WC_BYTES)           // qkv bf16: MROWS x 1536

// softmax scale (512^-0.5) * log2(e), folded into wq at cvt time: QK^T MFMA
// output is already in the exp2 domain. No max-subtract needed (scores' std
// ~0.07, validated R4).
#define SCALE2 (0.044194173824159216f * 1.4426950408889634f)

#if __has_builtin(__builtin_amdgcn_exp2f)
#define EXP2(x) __builtin_amdgcn_exp2f(x)
#else
#define EXP2(x) exp2f(x)
#endif
#if __has_builtin(__builtin_amdgcn_rcpf)
#define RCP(x) __builtin_amdgcn_rcpf(x)
#else
#define RCP(x) (1.0f / (x))
#endif

__device__ inline u16 f2b(float f) {
  union { float f; unsigned u; } a; a.f = f;
  unsigned u = a.u;
  return (u16)((u + 0x7FFFu + ((u >> 16) & 1u)) >> 16);
}

__device__ inline unsigned pack2(float a, float b) {  // v_cvt_pk_bf16_f32
  float2 f; f.x = a; f.y = b;
  union { __hip_bfloat162 h; unsigned u; } c;
  c.h = __float22bfloat162_rn(f);
  return c.u;
}

// ---------------- conversion kernels ----------------
__global__ __launch_bounds__(256) void cvt_x(const float* __restrict__ x, u16* __restrict__ xb) {
  int i = blockIdx.x * 256 + threadIdx.x;       // one float4 per thread
  float4 v = ((const float4*)x)[i];
  uint2 o; o.x = pack2(v.x, v.y); o.y = pack2(v.z, v.w);
  ((uint2*)xb)[i] = o;
}

__global__ __launch_bounds__(256) void cvt_w(const float* __restrict__ wq, const float* __restrict__ wk,
                                             const float* __restrict__ wv, u16* __restrict__ wcat) {
  int i = blockIdx.x * 256 + threadIdx.x;       // one float4 per thread
  int e = i * 4;
  int n = e >> 9;                                // output row 0..1535
  int k = e & 511;
  const float* src = (n < 512) ? (wq + (size_t)n * 512)
                   : (n < 1024) ? (wk + (size_t)(n - 512) * 512)
                                : (wv + (size_t)(n - 1024) * 512);
  const float sc = (n < 512) ? SCALE2 : 1.0f;   // fold softmax scale into Q
  float4 v = *(const float4*)(src + k);
  uint2 o; o.x = pack2(v.x * sc, v.y * sc); o.y = pack2(v.z * sc, v.w * sc);
  *(uint2*)(wcat + (size_t)n * 512 + k) = o;
}

// ---------------- async global->LDS ----------------
typedef __attribute__((address_space(1))) void* as1_void_p;
typedef __attribute__((address_space(3))) void* as3_void_p;

__device__ inline void async16(const u16* g, u16* l) {
#if __has_builtin(__builtin_amdgcn_global_load_lds)
  __builtin_amdgcn_global_load_lds((as1_void_p)g, (as3_void_p)l, 16, 0, 0);
#else
  *(uint4*)l = *(const uint4*)g;
#endif
}

// ---------------- QKV projection GEMM (m97-style, unchanged) ----------------
__global__ __launch_bounds__(256) void gemm_qkv(const u16* __restrict__ A, const u16* __restrict__ Bw,
                                                u16* __restrict__ Cm) {
  __shared__ u16 a_lds[128 * 32];
  __shared__ u16 b_lds[128 * 32];
  const int n0 = blockIdx.x * 128, m0 = blockIdx.y * 128;
  const int t = threadIdx.x, l = t & 63;
  const int wrow = ((t >> 7) & 1) * 64, wcol = ((t >> 6) & 1) * 64;
  const int lr = l & 15, lq = l >> 4;

  f32x4 acc[4][4] = {};

  for (int k0 = 0; k0 < 512; k0 += 32) {
    {
      int c0 = t, c1 = t + 256;
      async16(A  + (size_t)(m0 + (c0 >> 2)) * 512 + k0 + (c0 & 3) * 8, &a_lds[c0 * 8]);
      async16(A  + (size_t)(m0 + (c1 >> 2)) * 512 + k0 + (c1 & 3) * 8, &a_lds[c1 * 8]);
      async16(Bw + (size_t)(n0 + (c0 >> 2)) * 512 + k0 + (c0 & 3) * 8, &b_lds[c0 * 8]);
      async16(Bw + (size_t)(n0 + (c1 >> 2)) * 512 + k0 + (c1 & 3) * 8, &b_lds[c1 * 8]);
    }
    __syncthreads();
    bf16x8 af[4], bfr[4];
#pragma unroll
    for (int r = 0; r < 4; ++r) af[r]  = *(const bf16x8*)&a_lds[(wrow + r * 16 + lr) * 32 + lq * 8];
#pragma unroll
    for (int c = 0; c < 4; ++c) bfr[c] = *(const bf16x8*)&b_lds[(wcol + c * 16 + lr) * 32 + lq * 8];
#pragma unroll
    for (int r = 0; r < 4; ++r)
#pragma unroll
      for (int c = 0; c < 4; ++c)
        acc[r][c] = __builtin_amdgcn_mfma_f32_16x16x32_bf16(af[r], bfr[c], acc[r][c], 0, 0, 0);
    __syncthreads();
  }
#pragma unroll
  for (int r = 0; r < 4; ++r) {
#pragma unroll
    for (int i = 0; i < 4; ++i) {
      int m = m0 + wrow + r * 16 + lq * 4 + i;
      u16* crow = Cm + (size_t)m * NQKV + n0 + wcol;
#pragma unroll
      for (int c = 0; c < 4; ++c)
        crow[c * 16 + lr] = f2b(acc[r][c][i]);
    }
  }
}

// ---------------- V transpose + bias transpose ----------------
// blockIdx.y < 4 : qkv V-part (b,l,h,d) -> vT[(b*8+h)*64+d][l]
// blockIdx.y == 4: bias_table[rel][h] -> biasT[h][rel] (only x<32 active)
__global__ __launch_bounds__(256) void transpose_v(const u16* __restrict__ qkv, u16* __restrict__ vT,
                                                   const float* __restrict__ bias_table,
                                                   float* __restrict__ biasT) {
  if (blockIdx.y == 4) {
    if (blockIdx.x < 32) {
      int i = blockIdx.x * 256 + threadIdx.x;   // coalesced read of 1023*8
      if (i < 1023 * 8) {
        float v = bias_table[i];
        int rel = i >> 3, hh = i & 7;
        biasT[hh * 1024 + rel] = v;
      }
    }
    return;
  }
  const int bh = blockIdx.x;
  const int b = bh >> 3, h = bh & 7;
  const int lc0 = blockIdx.y * 128;
  __shared__ u16 tile[32 * 72];
  const int t = threadIdx.x;
  for (int lc = lc0; lc < lc0 + 128; lc += 32) {
    int lrow = t >> 3, dcol = (t & 7) * 8;
    const u16* src = qkv + (size_t)(b * 512 + lc + lrow) * NQKV + 1024 + h * 64 + dcol;
    *(uint4*)&tile[lrow * 72 + dcol] = *(const uint4*)src;
    __syncthreads();
    int d = t >> 2, lp = (t & 3) * 8;
    union { ushort4 v4[2]; u16 s[8]; } tmp;
#pragma unroll
    for (int j = 0; j < 8; ++j) tmp.s[j] = tile[(lp + j) * 72 + d];
    *(uint4*)&vT[(size_t)(bh * 64 + d) * 512 + lc + lp] = *(uint4*)&tmp;
    __syncthreads();
  }
}

// ---------------- fused attention (R11: 2 sub-tiles, thrash-free) ----------
// 256 thr / 4 waves. Block owns 64 queries of one (b,h) as 2 sequential
// 32-query sub-tiles reusing p_lds (reg/LDS footprint == R9). 2048 blocks.
// R10 post-mortem: 1024 blocks made the WHOLE grid co-resident -> per-XCD
// K/V working set 32 batches x 128KB = 4MB+ -> L2 thrash (FETCH 4.3x). At
// 2048 blocks, resident/XCD = 128 = 16 batches x 128KB = 2MB <= 4MB L2.
// Mapping flat = h | qpair<<3 | b<<6 keeps one head per XCD, consecutive
// blocks share (b,h) K/V. Ring/vmcnt structure identical to R9/R10 (FIFO
// re-audited: out-stores precede sub-tile-1 Q loads, so vmcnt(6) still
// retires exactly the Q+store set).
__global__ __launch_bounds__(256, 4) void attn_kernel(const u16* __restrict__ qkv, const u16* __restrict__ vT,
                                                      const float* __restrict__ biasT,
                                                      float* __restrict__ out) {
  __shared__ u16 p_lds[32 * 512];            // 32 KB, reused by both sub-tiles
  __shared__ float bias_lds[576];            // 575-wide slice covers 64 queries
  __shared__ float reds[2][4][32];           // double-buffered by sub-tile parity

  const int flat = blockIdx.x;               // 2048 blocks: h | (qpair<<3) | (b<<6)
  const int h = flat & 7;                    // one head per XCD
  const int q0 = ((flat >> 3) & 7) * 64;     // 8 qpairs of 64 queries
  const int b = flat >> 6;
  const int bh = b * 8 + h;
  const int t = threadIdx.x, l = t & 63, w = t >> 6;
  const int lr = l & 15, lq = l >> 4;

  // bias slice (coalesced, once per 64 queries):
  // bias for (q, key) = bias_lds[key + 63 - 32*j - qlocal], q = q0+32j+qlocal
  {
    const int rel0 = 448 - q0;
    const float* bsrc = biasT + h * 1024 + rel0;
    for (int i = t; i < 575; i += 256)
      bias_lds[i] = bsrc[i];
  }
  asm volatile("s_waitcnt vmcnt(0)" ::: "memory");  // fence bias fill off the rings

  const u16* kbase = qkv + (size_t)(b * 512 + w * 128 + lr) * NQKV + 512 + h * 64 + lq * 8;
  const u16* vrow  = vT  + (size_t)(bh * 64 + w * 16 + lr) * 512 + lq * 8;

#pragma unroll 1
  for (int j = 0; j < 2; ++j) {
    const int q0j = q0 + j * 32;

    // ---- Q loads (pinned asm, before the K ring -> FIFO position 0..3) ----
    u32x4 bqr[2][2];
    {
      const u16* q0r = qkv + (size_t)(b * 512 + q0j + lr) * NQKV + h * 64 + lq * 8;
      const u16* q1r = q0r + (size_t)16 * NQKV;
      asm volatile("global_load_dwordx4 %0, %2, off\n\t"
                   "global_load_dwordx4 %1, %2, off offset:64"
                   : "=&v"(bqr[0][0]), "=&v"(bqr[0][1]) : "v"(q0r));
      asm volatile("global_load_dwordx4 %0, %2, off\n\t"
                   "global_load_dwordx4 %1, %2, off offset:64"
                   : "=&v"(bqr[1][0]), "=&v"(bqr[1][1]) : "v"(q1r));
    }

    // ---- phase 1: S^T = K Q^T (exp2-domain), depth-4 K ring ----
    u32x4 akr[4][2];
    f32x4 sT[2][8];

#define KISSUE(slot, ct) { const u16* kr = kbase + (size_t)(ct) * 16 * NQKV;   \
    asm volatile("global_load_dwordx4 %0, %2, off\n\t"                         \
                 "global_load_dwordx4 %1, %2, off offset:64"                   \
                 : "=&v"(akr[slot][0]), "=&v"(akr[slot][1]) : "v"(kr)); }
#define KSTEP(ct, lit, doissue) {                                              \
    if (doissue) KISSUE(((ct) + 3) & 3, (ct) + 3)                              \
    asm volatile("s_waitcnt vmcnt(" lit ")"                                    \
                 : "+v"(akr[(ct) & 3][0]), "+v"(akr[(ct) & 3][1]));            \
    bf16x8 ak0 = __builtin_bit_cast(bf16x8, akr[(ct) & 3][0]);                 \
    bf16x8 ak1 = __builtin_bit_cast(bf16x8, akr[(ct) & 3][1]);                 \
    f32x4 a0 = {0.f, 0.f, 0.f, 0.f}, a1 = {0.f, 0.f, 0.f, 0.f};                \
    a0 = __builtin_amdgcn_mfma_f32_16x16x32_bf16(ak0, __builtin_bit_cast(bf16x8, bqr[0][0]), a0, 0, 0, 0); \
    a0 = __builtin_amdgcn_mfma_f32_16x16x32_bf16(ak1, __builtin_bit_cast(bf16x8, bqr[0][1]), a0, 0, 0, 0); \
    a1 = __builtin_amdgcn_mfma_f32_16x16x32_bf16(ak0, __builtin_bit_cast(bf16x8, bqr[1][0]), a1, 0, 0, 0); \
    a1 = __builtin_amdgcn_mfma_f32_16x16x32_bf16(ak1, __builtin_bit_cast(bf16x8, bqr[1][1]), a1, 0, 0, 0); \
    sT[0][ct] = a0; sT[1][ct] = a1; }

    KISSUE(0, 0) KISSUE(1, 1) KISSUE(2, 2)
    // Q (+ prior out-stores) retired once <=6 of the FIFO remain.
    asm volatile("s_waitcnt vmcnt(6)"
                 : "+v"(bqr[0][0]), "+v"(bqr[0][1]), "+v"(bqr[1][0]), "+v"(bqr[1][1]));
    KSTEP(0, "6", 1) KSTEP(1, "6", 1) KSTEP(2, "6", 1) KSTEP(3, "6", 1)
    KSTEP(4, "6", 1) KSTEP(5, "4", 0) KSTEP(6, "2", 0) KSTEP(7, "0", 0)
#undef KSTEP
#undef KISSUE

    // exp2 (raw v_exp_f32) + per-query sum; 4 partial accumulators per qt.
    float sq[2];
#pragma unroll
    for (int qt = 0; qt < 2; ++qt) {
      float s0 = 0.f, s1 = 0.f, s2 = 0.f, s3 = 0.f;
#pragma unroll
      for (int ct = 0; ct < 8; ++ct) {
        float e0 = EXP2(sT[qt][ct][0]);
        float e1 = EXP2(sT[qt][ct][1]);
        float e2 = EXP2(sT[qt][ct][2]);
        float e3 = EXP2(sT[qt][ct][3]);
        sT[qt][ct][0] = e0; sT[qt][ct][1] = e1;
        sT[qt][ct][2] = e2; sT[qt][ct][3] = e3;
        s0 += e0; s1 += e1; s2 += e2; s3 += e3;
      }
      sq[qt] = (s0 + s1) + (s2 + s3);
    }
    {
      float t0 = sq[0], t1 = sq[1];
      float u0 = __shfl_xor(t0, 16, 64), u1 = __shfl_xor(t1, 16, 64);
      t0 += u0; t1 += u1;
      u0 = __shfl_xor(t0, 32, 64); u1 = __shfl_xor(t1, 32, 64);
      sq[0] = t0 + u0; sq[1] = t1 + u1;
    }
    float (*rd)[32] = reds[j & 1];
    if (lq == 0) { rd[w][lr] = sq[0]; rd[w][16 + lr] = sq[1]; }

    // barrier 1: lgkm-only raw barrier. Also orders phase-3 p_lds reads of
    // sub-tile j-1 (program order) before this sub-tile's pack writes.
    asm volatile("s_waitcnt lgkmcnt(0)" ::: "memory");
    __builtin_amdgcn_s_barrier();
    asm volatile("" ::: "memory");

    float rinv[2];
#pragma unroll
    for (int qt = 0; qt < 2; ++qt)
      rinv[qt] = RCP(rd[0][qt * 16 + lr] + rd[1][qt * 16 + lr] +
                     rd[2][qt * 16 + lr] + rd[3][qt * 16 + lr]);

    // ---- V ring: 8 slots issued BEFORE the pack; stay in flight across the
    // raw barrier (no vmcnt drain) and land during phase 3. Warm for j=1.
    u32x4 avr[8];
#define VISSUE(slot, olit)                                                     \
    asm volatile("global_load_dwordx4 %0, %1, off offset:" olit                \
                 : "=&v"(avr[slot]) : "v"(vrow));
    VISSUE(0, "0")   VISSUE(1, "64")  VISSUE(2, "128") VISSUE(3, "192")
    VISSUE(4, "256") VISSUE(5, "320") VISSUE(6, "384") VISSUE(7, "448")

    // ---- pack P = e*rinv + bias -> bf16 LDS (swizzled b64 stores) ----
#define PACK_QT(qt)                                                            \
    {                                                                          \
      const int qlocal = (qt) * 16 + lr;                                       \
      u16* prow = p_lds + qlocal * 512;                                        \
      const int boff = w * 128 + lq * 4 + 63 - 32 * j - qlocal;                \
      _Pragma("unroll")                                                        \
      for (int ct = 0; ct < 8; ++ct) {                                         \
        const int gsw = w * 8 + (ct ^ (lr & 7));                               \
        float p0 = sT[qt][ct][0] * rinv[qt] + bias_lds[boff + ct * 16 + 0];    \
        float p1 = sT[qt][ct][1] * rinv[qt] + bias_lds[boff + ct * 16 + 1];    \
        float p2 = sT[qt][ct][2] * rinv[qt] + bias_lds[boff + ct * 16 + 2];    \
        float p3 = sT[qt][ct][3] * rinv[qt] + bias_lds[boff + ct * 16 + 3];    \
        uint2 pk; pk.x = pack2(p0, p1); pk.y = pack2(p2, p3);                  \
        *(uint2*)&prow[gsw * 16 + lq * 4] = pk;                                \
      }                                                                        \
    }
    PACK_QT(0)
    PACK_QT(1)
#undef PACK_QT

    // barrier 2: lgkm-only -- p_lds writes drained, V loads NOT.
    asm volatile("s_waitcnt lgkmcnt(0)" ::: "memory");
    __builtin_amdgcn_s_barrier();
    asm volatile("" ::: "memory");

    // ---- phase 3 (transposed): out^T(d,q) = V^T(d,k) P^T(k,q) ----
    f32x4 accP[2] = {};
    bf16x8 bp[2][2];
#define LDP(kb, qt) \
    (*(const bf16x8*)&p_lds[((qt) * 16 + lr) * 512 + \
      (((2 * (kb) + (lq >> 1)) & ~7) | (((2 * (kb) + (lq >> 1)) & 7) ^ (lr & 7))) * 16 + (lq & 1) * 8])
    bp[0][0] = LDP(0, 0);
    bp[0][1] = LDP(0, 1);
#define PVSTEP(kb, lit, doissue, olit) {                                       \
    asm volatile("s_waitcnt vmcnt(" lit ")" : "+v"(avr[(kb) & 7]));            \
    if ((kb) < 15) {                                                           \
      bp[((kb) + 1) & 1][0] = LDP((kb) + 1, 0);                                \
      bp[((kb) + 1) & 1][1] = LDP((kb) + 1, 1);                                \
    }                                                                          \
    bf16x8 av = __builtin_bit_cast(bf16x8, avr[(kb) & 7]);                     \
    accP[0] = __builtin_amdgcn_mfma_f32_16x16x32_bf16(av, bp[(kb) & 1][0], accP[0], 0, 0, 0); \
    accP[1] = __builtin_amdgcn_mfma_f32_16x16x32_bf16(av, bp[(kb) & 1][1], accP[1], 0, 0, 0); \
    if (doissue) VISSUE((kb) & 7, olit) }
    PVSTEP(0,  "7", 1, "512") PVSTEP(1,  "7", 1, "576")
    PVSTEP(2,  "7", 1, "640") PVSTEP(3,  "7", 1, "704")
    PVSTEP(4,  "7", 1, "768") PVSTEP(5,  "7", 1, "832")
    PVSTEP(6,  "7", 1, "896") PVSTEP(7,  "7", 1, "960")
    PVSTEP(8,  "7", 0, "0")   PVSTEP(9,  "6", 0, "0")
    PVSTEP(10, "5", 0, "0")   PVSTEP(11, "4", 0, "0")
    PVSTEP(12, "3", 0, "0")   PVSTEP(13, "2", 0, "0")
    PVSTEP(14, "1", 0, "0")   PVSTEP(15, "0", 0, "0")
#undef PVSTEP
#undef VISSUE
#undef LDP
    // D[m=d_off][n=q]: lane holds q = lr, d = w*16 + lq*4 + i -> f32x4 store
#pragma unroll
    for (int qt = 0; qt < 2; ++qt)
      *(f32x4*)&out[(size_t)(b * 512 + q0j + qt * 16 + lr) * 512 + h * 64 + w * 16 + lq * 4] = accP[qt];
  }
}

// ---------------- LayerNorm: 2 rows/block, float4 ----------------
__global__ __launch_bounds__(256) void ln_kernel(float* __restrict__ out,
                                                 const float* __restrict__ gamma,
                                                 const float* __restrict__ beta) {
  const int t = threadIdx.x;
  const int r2 = t >> 7;                       // row half: 0/1
  const int row = blockIdx.x * 2 + r2;
  const int c = (t & 127) * 4;
  float* p = out + (size_t)row * 512;
  float4 v = *(float4*)(p + c);
  float s = v.x + v.y + v.z + v.w;
  float s2 = v.x * v.x + v.y * v.y + v.z * v.z + v.w * v.w;
#pragma unroll
  for (int d = 1; d < 64; d <<= 1) { s += __shfl_xor(s, d, 64); s2 += __shfl_xor(s2, d, 64); }
  __shared__ float ps[4], ps2[4];
  const int wv = t >> 6;
  if ((t & 63) == 0) { ps[wv] = s; ps2[wv] = s2; }
  __syncthreads();
  s  = ps[r2 * 2]  + ps[r2 * 2 + 1];
  s2 = ps2[r2 * 2] + ps2[r2 * 2 + 1];
  float mu = s * (1.0f / 512.0f);
  float var = s2 * (1.0f / 512.0f) - mu * mu;
  float rs = rsqrtf(var + 1e-5f);
  float4 g = *(const float4*)(gamma + c);
  float4 bb = *(const float4*)(beta + c);
  v.x = g.x * (v.x - mu) * rs + bb.x;
  v.y = g.y * (v.y - mu) * rs + bb.y;
  v.z = g.z * (v.z - mu) * rs + bb.z;
  v.w = g.w * (v.w - mu) * rs + bb.w;
  *(float4*)(p + c) = v;
}

extern "C" void kernel_launch(void* const* d_in, const int* in_sizes, int n_in,
                              void* d_out, int out_size, void* d_ws, size_t ws_size,
                              hipStream_t stream) {
  const float* x    = (const float*)d_in[0];
  const float* wq   = (const float*)d_in[1];
  const float* wk   = (const float*)d_in[2];
  const float* wv   = (const float*)d_in[3];
  const float* bias = (const float*)d_in[4];
  const float* gamma = (const float*)d_in[5];
  const float* beta  = (const float*)d_in[6];
  float* out = (float*)d_out;

  char* ws = (char*)d_ws;
  u16* xb   = (u16*)ws;                       // x in bf16 (reused as vT afterwards)
  u16* wcat = (u16*)(ws + XB_BYTES);          // concat weights bf16 (wq pre-scaled)
  u16* qkv  = (u16*)(ws + QKV_OFF);           // MROWS x 1536 bf16
  u16* vT   = xb;                             // reuse: gemm done with xb before transpose
  float* biasT = (float*)(ws + XB_BYTES);     // reuse wcat region after gemm (8 x 1024 f32)

  cvt_x<<<dim3((MROWS * CC) / 4 / 256), 256, 0, stream>>>(x, xb);
  cvt_w<<<dim3((NQKV * CC) / 4 / 256), 256, 0, stream>>>(wq, wk, wv, wcat);
  gemm_qkv<<<dim3(NQKV / 128, MROWS / 128), 256, 0, stream>>>(xb, wcat, qkv);
  transpose_v<<<dim3(256, 5), 256, 0, stream>>>(qkv, vT, bias, biasT);
  attn_kernel<<<dim3(2048), 256, 0, stream>>>(qkv, vT, biasT, out);
  ln_kernel<<<dim3(MROWS / 2), 256, 0, stream>>>(out, gamma, beta);
}

// Round 8
// 229.493 us; speedup vs baseline: 1.0510x; 1.0510x over previous
//
#include <hip/hip_runtime.h>
#include <hip/hip_bf16.h>

typedef unsigned short u16;
typedef __attribute__((ext_vector_type(8))) __bf16 bf16x8;
typedef __attribute__((ext_vector_type(4))) float f32x4;
typedef __attribute__((ext_vector_type(4))) unsigned int u32x4;

// Problem dims
#define BB 32
#define LL 512
#define CC 512
#define HH 8
#define DH 64
#define MROWS (BB * LL)        // 16384
#define NQKV  (3 * CC)         // 1536

// workspace layout (bytes)
#define XB_BYTES ((size_t)MROWS * CC * 2)        // 16,777,216  (x bf16; later reused as vT)
#define WC_BYTES ((size_t)NQKV * CC * 2)         //  1,572,864  (wq|wk|wv bf16; dead after gemm -> biasT)
#define QKV_OFF  (XB_BYTES + WC_BYTES)           // qkv bf16: MROWS x 1536

// softmax scale (512^-0.5) * log2(e), folded into wq at cvt time: QK^T MFMA
// output is already in the exp2 domain. No max-subtract needed (scores' std
// ~0.07, validated R4).
#define SCALE2 (0.044194173824159216f * 1.4426950408889634f)

#if __has_builtin(__builtin_amdgcn_exp2f)
#define EXP2(x) __builtin_amdgcn_exp2f(x)
#else
#define EXP2(x) exp2f(x)
#endif
#if __has_builtin(__builtin_amdgcn_rcpf)
#define RCP(x) __builtin_amdgcn_rcpf(x)
#else
#define RCP(x) (1.0f / (x))
#endif

__device__ inline u16 f2b(float f) {
  union { float f; unsigned u; } a; a.f = f;
  unsigned u = a.u;
  return (u16)((u + 0x7FFFu + ((u >> 16) & 1u)) >> 16);
}

__device__ inline unsigned pack2(float a, float b) {  // v_cvt_pk_bf16_f32
  float2 f; f.x = a; f.y = b;
  union { __hip_bfloat162 h; unsigned u; } c;
  c.h = __float22bfloat162_rn(f);
  return c.u;
}

// ---------------- conversion kernels ----------------
__global__ __launch_bounds__(256) void cvt_x(const float* __restrict__ x, u16* __restrict__ xb) {
  int i = blockIdx.x * 256 + threadIdx.x;       // one float4 per thread
  float4 v = ((const float4*)x)[i];
  uint2 o; o.x = pack2(v.x, v.y); o.y = pack2(v.z, v.w);
  ((uint2*)xb)[i] = o;
}

__global__ __launch_bounds__(256) void cvt_w(const float* __restrict__ wq, const float* __restrict__ wk,
                                             const float* __restrict__ wv, u16* __restrict__ wcat) {
  int i = blockIdx.x * 256 + threadIdx.x;       // one float4 per thread
  int e = i * 4;
  int n = e >> 9;                                // output row 0..1535
  int k = e & 511;
  const float* src = (n < 512) ? (wq + (size_t)n * 512)
                   : (n < 1024) ? (wk + (size_t)(n - 512) * 512)
                                : (wv + (size_t)(n - 1024) * 512);
  const float sc = (n < 512) ? SCALE2 : 1.0f;   // fold softmax scale into Q
  float4 v = *(const float4*)(src + k);
  uint2 o; o.x = pack2(v.x * sc, v.y * sc); o.y = pack2(v.z * sc, v.w * sc);
  *(uint2*)(wcat + (size_t)n * 512 + k) = o;
}

// ---------------- async global->LDS ----------------
typedef __attribute__((address_space(1))) void* as1_void_p;
typedef __attribute__((address_space(3))) void* as3_void_p;

__device__ inline void async16(const u16* g, u16* l) {
#if __has_builtin(__builtin_amdgcn_global_load_lds)
  __builtin_amdgcn_global_load_lds((as1_void_p)g, (as3_void_p)l, 16, 0, 0);
#else
  *(uint4*)l = *(const uint4*)g;
#endif
}

// ---------------- QKV projection GEMM (m97-style K-loop) --------------------
// R12: epilogue rework only. MFMA operands SWAPPED (mfma(bfr, af)) — A/B
// fragment layouts are symmetric for 16x16x32, so D holds the same C tile
// with transposed per-lane ownership: lane lr = m-row, regs = 4 CONSECUTIVE n.
// Store: 16 coalesced uint2 (8B) instead of 64 scattered u16; 32 pack2
// instead of 64 f2b. K-loop untouched.
__global__ __launch_bounds__(256) void gemm_qkv(const u16* __restrict__ A, const u16* __restrict__ Bw,
                                                u16* __restrict__ Cm) {
  __shared__ u16 a_lds[128 * 32];
  __shared__ u16 b_lds[128 * 32];
  const int n0 = blockIdx.x * 128, m0 = blockIdx.y * 128;
  const int t = threadIdx.x, l = t & 63;
  const int wrow = ((t >> 7) & 1) * 64, wcol = ((t >> 6) & 1) * 64;
  const int lr = l & 15, lq = l >> 4;

  f32x4 acc[4][4] = {};

  for (int k0 = 0; k0 < 512; k0 += 32) {
    {
      int c0 = t, c1 = t + 256;
      async16(A  + (size_t)(m0 + (c0 >> 2)) * 512 + k0 + (c0 & 3) * 8, &a_lds[c0 * 8]);
      async16(A  + (size_t)(m0 + (c1 >> 2)) * 512 + k0 + (c1 & 3) * 8, &a_lds[c1 * 8]);
      async16(Bw + (size_t)(n0 + (c0 >> 2)) * 512 + k0 + (c0 & 3) * 8, &b_lds[c0 * 8]);
      async16(Bw + (size_t)(n0 + (c1 >> 2)) * 512 + k0 + (c1 & 3) * 8, &b_lds[c1 * 8]);
    }
    __syncthreads();
    bf16x8 af[4], bfr[4];
#pragma unroll
    for (int r = 0; r < 4; ++r) af[r]  = *(const bf16x8*)&a_lds[(wrow + r * 16 + lr) * 32 + lq * 8];
#pragma unroll
    for (int c = 0; c < 4; ++c) bfr[c] = *(const bf16x8*)&b_lds[(wcol + c * 16 + lr) * 32 + lq * 8];
#pragma unroll
    for (int r = 0; r < 4; ++r)
#pragma unroll
      for (int c = 0; c < 4; ++c)
        acc[r][c] = __builtin_amdgcn_mfma_f32_16x16x32_bf16(bfr[c], af[r], acc[r][c], 0, 0, 0);
    __syncthreads();
  }
  // D'[m'][n']: col(lane&15)=lr -> C m-index-in-tile; row(lq*4+i) -> C n-index.
#pragma unroll
  for (int r = 0; r < 4; ++r) {
    const int m = m0 + wrow + r * 16 + lr;
    u16* crow = Cm + (size_t)m * NQKV + n0 + wcol + lq * 4;
#pragma unroll
    for (int c = 0; c < 4; ++c) {
      uint2 pk;
      pk.x = pack2(acc[r][c][0], acc[r][c][1]);
      pk.y = pack2(acc[r][c][2], acc[r][c][3]);
      *(uint2*)(crow + c * 16) = pk;
    }
  }
}

// ---------------- V transpose + bias transpose ----------------
// blockIdx.y < 4 : qkv V-part (b,l,h,d) -> vT[(b*8+h)*64+d][l]
// blockIdx.y == 4: bias_table[rel][h] -> biasT[h][rel] (only x<32 active)
__global__ __launch_bounds__(256) void transpose_v(const u16* __restrict__ qkv, u16* __restrict__ vT,
                                                   const float* __restrict__ bias_table,
                                                   float* __restrict__ biasT) {
  if (blockIdx.y == 4) {
    if (blockIdx.x < 32) {
      int i = blockIdx.x * 256 + threadIdx.x;   // coalesced read of 1023*8
      if (i < 1023 * 8) {
        float v = bias_table[i];
        int rel = i >> 3, hh = i & 7;
        biasT[hh * 1024 + rel] = v;
      }
    }
    return;
  }
  const int bh = blockIdx.x;
  const int b = bh >> 3, h = bh & 7;
  const int lc0 = blockIdx.y * 128;
  __shared__ u16 tile[32 * 72];
  const int t = threadIdx.x;
  for (int lc = lc0; lc < lc0 + 128; lc += 32) {
    int lrow = t >> 3, dcol = (t & 7) * 8;
    const u16* src = qkv + (size_t)(b * 512 + lc + lrow) * NQKV + 1024 + h * 64 + dcol;
    *(uint4*)&tile[lrow * 72 + dcol] = *(const uint4*)src;
    __syncthreads();
    int d = t >> 2, lp = (t & 3) * 8;
    union { ushort4 v4[2]; u16 s[8]; } tmp;
#pragma unroll
    for (int j = 0; j < 8; ++j) tmp.s[j] = tile[(lp + j) * 72 + d];
    *(uint4*)&vT[(size_t)(bh * 64 + d) * 512 + lc + lp] = *(uint4*)&tmp;
    __syncthreads();
  }
}

// ---------------- fused attention (R12 = exact R9: occupancy-first, rings) --
// R10/R11 post-mortem: ANY multi-sub-tile looping thrashes L2 (out-store
// stream evicts K/V between sub-tiles; FETCH 24.6 -> 72-107MB). One 32-query
// sub-tile per block, 4096 blocks, is the verified optimum (77 us). Reverted
// verbatim to the R9 kernel.
__global__ __launch_bounds__(256, 4) void attn_kernel(const u16* __restrict__ qkv, const u16* __restrict__ vT,
                                                      const float* __restrict__ biasT,
                                                      float* __restrict__ out) {
  __shared__ u16 p_lds[32 * 512];            // 32 KB
  __shared__ float bias_lds[544];
  __shared__ float reds[4][32];

  const int flat = blockIdx.x;
  const int bh = ((flat >> 7) << 3) | (flat & 7);
  const int q0 = ((flat >> 3) & 15) * 32;
  const int b = bh >> 3, h = bh & 7;
  const int t = threadIdx.x, l = t & 63, w = t >> 6;
  const int lr = l & 15, lq = l >> 4;

  // bias slice (coalesced): bias for (q,key) = bias_lds[key + 31 - (q - q0)]
  {
    const int rel0 = 480 - q0;
    const float* bsrc = biasT + h * 1024 + rel0;
    for (int i = t; i < 543; i += 256)
      bias_lds[i] = bsrc[i];
  }
  // drain the bias-fill global loads so the counted K/V rings below see only
  // their own vmcnt traffic ("memory" also fences compiler load motion).
  asm volatile("s_waitcnt vmcnt(0)" ::: "memory");

  // Q B-frags (pre-scaled by SCALE2 via cvt_w); compiler-managed loads -- any
  // compiler-inserted wait before their first use is conservative vs the ring.
  bf16x8 bq[2][2];
#pragma unroll
  for (int qt = 0; qt < 2; ++qt) {
    const u16* qrow = qkv + (size_t)(b * 512 + q0 + qt * 16 + lr) * NQKV + h * 64;
    bq[qt][0] = *(const bf16x8*)(qrow + lq * 8);
    bq[qt][1] = *(const bf16x8*)(qrow + 32 + lq * 8);
  }

  // ---- phase 1: S^T = K Q^T (already exp2-domain), depth-4 K ring ----
  const u16* kbase = qkv + (size_t)(b * 512 + w * 128 + lr) * NQKV + 512 + h * 64 + lq * 8;
  u32x4 akr[4][2];
  f32x4 sT[2][8];

#define KISSUE(slot, ct) { const u16* kr = kbase + (size_t)(ct) * 16 * NQKV;   \
    asm volatile("global_load_dwordx4 %0, %2, off\n\t"                         \
                 "global_load_dwordx4 %1, %2, off offset:64"                   \
                 : "=&v"(akr[slot][0]), "=&v"(akr[slot][1]) : "v"(kr)); }
  // wait literal = 2 * (pairs issued after pair ct); tied outputs give the
  // MFMAs a data-dep through the wait (no sched_barrier needed, rule #18).
#define KSTEP(ct, lit, doissue) {                                              \
    if (doissue) KISSUE(((ct) + 3) & 3, (ct) + 3)                              \
    asm volatile("s_waitcnt vmcnt(" lit ")"                                    \
                 : "+v"(akr[(ct) & 3][0]), "+v"(akr[(ct) & 3][1]));            \
    bf16x8 ak0 = __builtin_bit_cast(bf16x8, akr[(ct) & 3][0]);                 \
    bf16x8 ak1 = __builtin_bit_cast(bf16x8, akr[(ct) & 3][1]);                 \
    f32x4 a0 = {0.f, 0.f, 0.f, 0.f}, a1 = {0.f, 0.f, 0.f, 0.f};                \
    a0 = __builtin_amdgcn_mfma_f32_16x16x32_bf16(ak0, bq[0][0], a0, 0, 0, 0);  \
    a0 = __builtin_amdgcn_mfma_f32_16x16x32_bf16(ak1, bq[0][1], a0, 0, 0, 0);  \
    a1 = __builtin_amdgcn_mfma_f32_16x16x32_bf16(ak0, bq[1][0], a1, 0, 0, 0);  \
    a1 = __builtin_amdgcn_mfma_f32_16x16x32_bf16(ak1, bq[1][1], a1, 0, 0, 0);  \
    sT[0][ct] = a0; sT[1][ct] = a1; }

  KISSUE(0, 0) KISSUE(1, 1) KISSUE(2, 2)
  KSTEP(0, "6", 1) KSTEP(1, "6", 1) KSTEP(2, "6", 1) KSTEP(3, "6", 1)
  KSTEP(4, "6", 1) KSTEP(5, "4", 0) KSTEP(6, "2", 0) KSTEP(7, "0", 0)
#undef KSTEP
#undef KISSUE

  // exp2 (raw v_exp_f32) + per-query sum; 4 partial accumulators per qt.
  float sq[2];
#pragma unroll
  for (int qt = 0; qt < 2; ++qt) {
    float s0 = 0.f, s1 = 0.f, s2 = 0.f, s3 = 0.f;
#pragma unroll
    for (int ct = 0; ct < 8; ++ct) {
      float e0 = EXP2(sT[qt][ct][0]);
      float e1 = EXP2(sT[qt][ct][1]);
      float e2 = EXP2(sT[qt][ct][2]);
      float e3 = EXP2(sT[qt][ct][3]);
      sT[qt][ct][0] = e0; sT[qt][ct][1] = e1;
      sT[qt][ct][2] = e2; sT[qt][ct][3] = e3;
      s0 += e0; s1 += e1; s2 += e2; s3 += e3;
    }
    sq[qt] = (s0 + s1) + (s2 + s3);
  }
  {
    float t0 = sq[0], t1 = sq[1];
    float u0 = __shfl_xor(t0, 16, 64), u1 = __shfl_xor(t1, 16, 64);
    t0 += u0; t1 += u1;
    u0 = __shfl_xor(t0, 32, 64); u1 = __shfl_xor(t1, 32, 64);
    sq[0] = t0 + u0; sq[1] = t1 + u1;
  }
  if (lq == 0) { reds[w][lr] = sq[0]; reds[w][16 + lr] = sq[1]; }

  // barrier 1: lgkm-only raw barrier (no global traffic to protect here).
  asm volatile("s_waitcnt lgkmcnt(0)" ::: "memory");
  __builtin_amdgcn_s_barrier();
  asm volatile("" ::: "memory");

  float rinv[2];
#pragma unroll
  for (int qt = 0; qt < 2; ++qt)
    rinv[qt] = RCP(reds[0][qt * 16 + lr] + reds[1][qt * 16 + lr] +
                   reds[2][qt * 16 + lr] + reds[3][qt * 16 + lr]);

  // ---- V ring: 8 slots (32 regs) issued BEFORE the pack; they stay in
  // flight across the raw barrier (no vmcnt drain) and land during phase 3.
  const u16* vrow = vT + (size_t)(bh * 64 + w * 16 + lr) * 512 + lq * 8;
  u32x4 avr[8];
#define VISSUE(slot, olit)                                                     \
  asm volatile("global_load_dwordx4 %0, %1, off offset:" olit                  \
               : "=&v"(avr[slot]) : "v"(vrow));
  VISSUE(0, "0")   VISSUE(1, "64")  VISSUE(2, "128") VISSUE(3, "192")
  VISSUE(4, "256") VISSUE(5, "320") VISSUE(6, "384") VISSUE(7, "448")

  // ---- pack P = e*rinv + bias -> bf16 LDS (swizzled b64 stores) ----
#define PACK_QT(qt)                                                            \
  {                                                                            \
    const int qlocal = (qt) * 16 + lr;                                         \
    u16* prow = p_lds + qlocal * 512;                                          \
    const int boff = w * 128 + lq * 4 + 31 - qlocal;                           \
    _Pragma("unroll")                                                          \
    for (int ct = 0; ct < 8; ++ct) {                                           \
      const int gsw = w * 8 + (ct ^ (lr & 7));                                 \
      float p0 = sT[qt][ct][0] * rinv[qt] + bias_lds[boff + ct * 16 + 0];      \
      float p1 = sT[qt][ct][1] * rinv[qt] + bias_lds[boff + ct * 16 + 1];      \
      float p2 = sT[qt][ct][2] * rinv[qt] + bias_lds[boff + ct * 16 + 2];      \
      float p3 = sT[qt][ct][3] * rinv[qt] + bias_lds[boff + ct * 16 + 3];      \
      uint2 pk; pk.x = pack2(p0, p1); pk.y = pack2(p2, p3);                    \
      *(uint2*)&prow[gsw * 16 + lq * 4] = pk;                                  \
    }                                                                          \
  }
  PACK_QT(0)
  PACK_QT(1)
#undef PACK_QT

  // barrier 2: lgkm-only raw barrier -- p_lds writes drained, V loads NOT.
  asm volatile("s_waitcnt lgkmcnt(0)" ::: "memory");
  __builtin_amdgcn_s_barrier();
  asm volatile("" ::: "memory");

  // ---- phase 3 (transposed): out^T(d,q) = V^T(d,k) P^T(k,q) ----
  // V ring continues: consume slot kb&7, issue key kb+8 into the same slot.
  // bp depth-2 pipeline on the LDS P reads (compiler-managed lgkmcnt).
  f32x4 accP[2] = {};
  bf16x8 bp[2][2];
#define LDP(kb, qt) \
  (*(const bf16x8*)&p_lds[((qt) * 16 + lr) * 512 + \
    (((2 * (kb) + (lq >> 1)) & ~7) | (((2 * (kb) + (lq >> 1)) & 7) ^ (lr & 7))) * 16 + (lq & 1) * 8])
  bp[0][0] = LDP(0, 0);
  bp[0][1] = LDP(0, 1);
#define PVSTEP(kb, lit, doissue, olit) {                                       \
    asm volatile("s_waitcnt vmcnt(" lit ")" : "+v"(avr[(kb) & 7]));            \
    if ((kb) < 15) {                                                           \
      bp[((kb) + 1) & 1][0] = LDP((kb) + 1, 0);                                \
      bp[((kb) + 1) & 1][1] = LDP((kb) + 1, 1);                                \
    }                                                                          \
    bf16x8 av = __builtin_bit_cast(bf16x8, avr[(kb) & 7]);                     \
    accP[0] = __builtin_amdgcn_mfma_f32_16x16x32_bf16(av, bp[(kb) & 1][0], accP[0], 0, 0, 0); \
    accP[1] = __builtin_amdgcn_mfma_f32_16x16x32_bf16(av, bp[(kb) & 1][1], accP[1], 0, 0, 0); \
    if (doissue) VISSUE((kb) & 7, olit) }
  PVSTEP(0,  "7", 1, "512") PVSTEP(1,  "7", 1, "576")
  PVSTEP(2,  "7", 1, "640") PVSTEP(3,  "7", 1, "704")
  PVSTEP(4,  "7", 1, "768") PVSTEP(5,  "7", 1, "832")
  PVSTEP(6,  "7", 1, "896") PVSTEP(7,  "7", 1, "960")
  PVSTEP(8,  "7", 0, "0")   PVSTEP(9,  "6", 0, "0")
  PVSTEP(10, "5", 0, "0")   PVSTEP(11, "4", 0, "0")
  PVSTEP(12, "3", 0, "0")   PVSTEP(13, "2", 0, "0")
  PVSTEP(14, "1", 0, "0")   PVSTEP(15, "0", 0, "0")
#undef PVSTEP
#undef VISSUE
#undef LDP
  // D[m=d_off][n=q]: lane holds q = lr, d = w*16 + lq*4 + i  -> f32x4 store
#pragma unroll
  for (int qt = 0; qt < 2; ++qt)
    *(f32x4*)&out[(size_t)(b * 512 + q0 + qt * 16 + lr) * 512 + h * 64 + w * 16 + lq * 4] = accP[qt];
}

// ---------------- LayerNorm: 2 rows/block, float4 ----------------
__global__ __launch_bounds__(256) void ln_kernel(float* __restrict__ out,
                                                 const float* __restrict__ gamma,
                                                 const float* __restrict__ beta) {
  const int t = threadIdx.x;
  const int r2 = t >> 7;                       // row half: 0/1
  const int row = blockIdx.x * 2 + r2;
  const int c = (t & 127) * 4;
  float* p = out + (size_t)row * 512;
  float4 v = *(float4*)(p + c);
  float s = v.x + v.y + v.z + v.w;
  float s2 = v.x * v.x + v.y * v.y + v.z * v.z + v.w * v.w;
#pragma unroll
  for (int d = 1; d < 64; d <<= 1) { s += __shfl_xor(s, d, 64); s2 += __shfl_xor(s2, d, 64); }
  __shared__ float ps[4], ps2[4];
  const int wv = t >> 6;
  if ((t & 63) == 0) { ps[wv] = s; ps2[wv] = s2; }
  __syncthreads();
  s  = ps[r2 * 2]  + ps[r2 * 2 + 1];
  s2 = ps2[r2 * 2] + ps2[r2 * 2 + 1];
  float mu = s * (1.0f / 512.0f);
  float var = s2 * (1.0f / 512.0f) - mu * mu;
  float rs = rsqrtf(var + 1e-5f);
  float4 g = *(const float4*)(gamma + c);
  float4 bb = *(const float4*)(beta + c);
  v.x = g.x * (v.x - mu) * rs + bb.x;
  v.y = g.y * (v.y - mu) * rs + bb.y;
  v.z = g.z * (v.z - mu) * rs + bb.z;
  v.w = g.w * (v.w - mu) * rs + bb.w;
  *(float4*)(p + c) = v;
}

extern "C" void kernel_launch(void* const* d_in, const int* in_sizes, int n_in,
                              void* d_out, int out_size, void* d_ws, size_t ws_size,
                              hipStream_t stream) {
  const float* x    = (const float*)d_in[0];
  const float* wq   = (const float*)d_in[1];
  const float* wk   = (const float*)d_in[2];
  const float* wv   = (const float*)d_in[3];
  const float* bias = (const float*)d_in[4];
  const float* gamma = (const float*)d_in[5];
  const float* beta  = (const float*)d_in[6];
  float* out = (float*)d_out;

  char* ws = (char*)d_ws;
  u16* xb   = (u16*)ws;                       // x in bf16 (reused as vT afterwards)
  u16* wcat = (u16*)(ws + XB_BYTES);          // concat weights bf16 (wq pre-scaled)
  u16* qkv  = (u16*)(ws + QKV_OFF);           // MROWS x 1536 bf16
  u16* vT   = xb;                             // reuse: gemm done with xb before transpose
  float* biasT = (float*)(ws + XB_BYTES);     // reuse wcat region after gemm (8 x 1024 f32)

  cvt_x<<<dim3((MROWS * CC) / 4 / 256), 256, 0, stream>>>(x, xb);
  cvt_w<<<dim3((NQKV * CC) / 4 / 256), 256, 0, stream>>>(wq, wk, wv, wcat);
  gemm_qkv<<<dim3(NQKV / 128, MROWS / 128), 256, 0, stream>>>(xb, wcat, qkv);
  transpose_v<<<dim3(256, 5), 256, 0, stream>>>(qkv, vT, bias, biasT);
  attn_kernel<<<dim3(16 * 256), 256, 0, stream>>>(qkv, vT, biasT, out);
  ln_kernel<<<dim3(MROWS / 2), 256, 0, stream>>>(out, gamma, beta);
}

// Round 9
// 226.661 us; speedup vs baseline: 1.0641x; 1.0125x over previous
//
#include <hip/hip_runtime.h>
#include <hip/hip_bf16.h>

typedef unsigned short u16;
typedef __attribute__((ext_vector_type(8))) __bf16 bf16x8;
typedef __attribute__((ext_vector_type(4))) float f32x4;
typedef __attribute__((ext_vector_type(4))) unsigned int u32x4;

// Problem dims
#define BB 32
#define LL 512
#define CC 512
#define HH 8
#define DH 64
#define MROWS (BB * LL)        // 16384
#define NQKV  (3 * CC)         // 1536

// workspace layout (bytes)
#define XB_BYTES ((size_t)MROWS * CC * 2)        // 16,777,216  (x bf16; later reused as vT)
#define WC_BYTES ((size_t)NQKV * CC * 2)         //  1,572,864  (wq|wk|wv bf16; dead after gemm -> biasT)
#define QKV_OFF  (XB_BYTES + WC_BYTES)           // qkv bf16: MROWS x 1536

// softmax scale (512^-0.5) * log2(e), folded into wq at cvt time: QK^T MFMA
// output is already in the exp2 domain. No max-subtract needed (scores' std
// ~0.07, validated R4).
#define SCALE2 (0.044194173824159216f * 1.4426950408889634f)

#if __has_builtin(__builtin_amdgcn_exp2f)
#define EXP2(x) __builtin_amdgcn_exp2f(x)
#else
#define EXP2(x) exp2f(x)
#endif
#if __has_builtin(__builtin_amdgcn_rcpf)
#define RCP(x) __builtin_amdgcn_rcpf(x)
#else
#define RCP(x) (1.0f / (x))
#endif

__device__ inline u16 f2b(float f) {
  union { float f; unsigned u; } a; a.f = f;
  unsigned u = a.u;
  return (u16)((u + 0x7FFFu + ((u >> 16) & 1u)) >> 16);
}

__device__ inline unsigned pack2(float a, float b) {  // v_cvt_pk_bf16_f32
  float2 f; f.x = a; f.y = b;
  union { __hip_bfloat162 h; unsigned u; } c;
  c.h = __float22bfloat162_rn(f);
  return c.u;
}

// ---------------- conversion kernels ----------------
__global__ __launch_bounds__(256) void cvt_x(const float* __restrict__ x, u16* __restrict__ xb) {
  int i = blockIdx.x * 256 + threadIdx.x;       // one float4 per thread
  float4 v = ((const float4*)x)[i];
  uint2 o; o.x = pack2(v.x, v.y); o.y = pack2(v.z, v.w);
  ((uint2*)xb)[i] = o;
}

__global__ __launch_bounds__(256) void cvt_w(const float* __restrict__ wq, const float* __restrict__ wk,
                                             const float* __restrict__ wv, u16* __restrict__ wcat) {
  int i = blockIdx.x * 256 + threadIdx.x;       // one float4 per thread
  int e = i * 4;
  int n = e >> 9;                                // output row 0..1535
  int k = e & 511;
  const float* src = (n < 512) ? (wq + (size_t)n * 512)
                   : (n < 1024) ? (wk + (size_t)(n - 512) * 512)
                                : (wv + (size_t)(n - 1024) * 512);
  const float sc = (n < 512) ? SCALE2 : 1.0f;   // fold softmax scale into Q
  float4 v = *(const float4*)(src + k);
  uint2 o; o.x = pack2(v.x * sc, v.y * sc); o.y = pack2(v.z * sc, v.w * sc);
  *(uint2*)(wcat + (size_t)n * 512 + k) = o;
}

// ---------------- async global->LDS ----------------
typedef __attribute__((address_space(1))) void* as1_void_p;
typedef __attribute__((address_space(3))) void* as3_void_p;

__device__ inline void async16(const u16* g, u16* l) {
#if __has_builtin(__builtin_amdgcn_global_load_lds)
  __builtin_amdgcn_global_load_lds((as1_void_p)g, (as3_void_p)l, 16, 0, 0);
#else
  *(uint4*)l = *(const uint4*)g;
#endif
}

// ---------------- QKV projection GEMM (R13: BK=64, swizzled staging) --------
// m97 family, BK 32 -> 64: 8 two-barrier stages instead of 16 (halves the
// vmcnt(0)-before-barrier drain events, the documented ~20% m97 stall), 32
// MFMAs per stage. LDS [128][64] u16 has 128B row stride -> naive reads would
// be a 16-way bank conflict (G4), so staging pre-swizzles the GLOBAL source
// (rule #21: global_load_lds dest must stay linear): physical col-block
// p = q ^ (row&7); reads apply the same XOR -> 2-way (free) ds_read_b128.
// Epilogue/operand order = verified R5 form (R12's swap was a regression).
__global__ __launch_bounds__(256) void gemm_qkv(const u16* __restrict__ A, const u16* __restrict__ Bw,
                                                u16* __restrict__ Cm) {
  __shared__ u16 a_lds[128 * 64];     // 16 KB
  __shared__ u16 b_lds[128 * 64];     // 16 KB
  const int n0 = blockIdx.x * 128, m0 = blockIdx.y * 128;
  const int t = threadIdx.x, l = t & 63;
  const int wrow = ((t >> 7) & 1) * 64, wcol = ((t >> 6) & 1) * 64;
  const int lr = l & 15, lq = l >> 4;
  const int sxor = lr & 7;            // read-side swizzle: row&7 == lr&7 here

  f32x4 acc[4][4] = {};

  for (int k0 = 0; k0 < 512; k0 += 64) {
    // stage 128x64 of A and B: 4 transfers/thread/matrix, source pre-swizzled
#pragma unroll
    for (int cc = 0; cc < 4; ++cc) {
      const int c = t + cc * 256;
      const int row = c >> 3, p = c & 7;
      const int q = p ^ (row & 7);               // logical col-block
      async16(A  + (size_t)(m0 + row) * 512 + k0 + q * 8, &a_lds[c * 8]);
      async16(Bw + (size_t)(n0 + row) * 512 + k0 + q * 8, &b_lds[c * 8]);
    }
    __syncthreads();
#pragma unroll
    for (int kk = 0; kk < 2; ++kk) {
      const int p = (lq + 4 * kk) ^ sxor;        // physical col-block to read
      bf16x8 af[4], bfr[4];
#pragma unroll
      for (int r = 0; r < 4; ++r) af[r]  = *(const bf16x8*)&a_lds[(wrow + r * 16 + lr) * 64 + p * 8];
#pragma unroll
      for (int c = 0; c < 4; ++c) bfr[c] = *(const bf16x8*)&b_lds[(wcol + c * 16 + lr) * 64 + p * 8];
#pragma unroll
      for (int r = 0; r < 4; ++r)
#pragma unroll
        for (int c = 0; c < 4; ++c)
          acc[r][c] = __builtin_amdgcn_mfma_f32_16x16x32_bf16(af[r], bfr[c], acc[r][c], 0, 0, 0);
    }
    __syncthreads();
  }
#pragma unroll
  for (int r = 0; r < 4; ++r) {
#pragma unroll
    for (int i = 0; i < 4; ++i) {
      int m = m0 + wrow + r * 16 + lq * 4 + i;
      u16* crow = Cm + (size_t)m * NQKV + n0 + wcol;
#pragma unroll
      for (int c = 0; c < 4; ++c)
        crow[c * 16 + lr] = f2b(acc[r][c][i]);
    }
  }
}

// ---------------- V transpose + bias transpose ----------------
// blockIdx.y < 4 : qkv V-part (b,l,h,d) -> vT[(b*8+h)*64+d][l]
// blockIdx.y == 4: bias_table[rel][h] -> biasT[h][rel] (only x<32 active)
__global__ __launch_bounds__(256) void transpose_v(const u16* __restrict__ qkv, u16* __restrict__ vT,
                                                   const float* __restrict__ bias_table,
                                                   float* __restrict__ biasT) {
  if (blockIdx.y == 4) {
    if (blockIdx.x < 32) {
      int i = blockIdx.x * 256 + threadIdx.x;   // coalesced read of 1023*8
      if (i < 1023 * 8) {
        float v = bias_table[i];
        int rel = i >> 3, hh = i & 7;
        biasT[hh * 1024 + rel] = v;
      }
    }
    return;
  }
  const int bh = blockIdx.x;
  const int b = bh >> 3, h = bh & 7;
  const int lc0 = blockIdx.y * 128;
  __shared__ u16 tile[32 * 72];
  const int t = threadIdx.x;
  for (int lc = lc0; lc < lc0 + 128; lc += 32) {
    int lrow = t >> 3, dcol = (t & 7) * 8;
    const u16* src = qkv + (size_t)(b * 512 + lc + lrow) * NQKV + 1024 + h * 64 + dcol;
    *(uint4*)&tile[lrow * 72 + dcol] = *(const uint4*)src;
    __syncthreads();
    int d = t >> 2, lp = (t & 3) * 8;
    union { ushort4 v4[2]; u16 s[8]; } tmp;
#pragma unroll
    for (int j = 0; j < 8; ++j) tmp.s[j] = tile[(lp + j) * 72 + d];
    *(uint4*)&vT[(size_t)(bh * 64 + d) * 512 + lc + lp] = *(uint4*)&tmp;
    __syncthreads();
  }
}

// ---------------- fused attention (= exact R9: occupancy-first, rings) ------
// Verified optimum of this structure family: one 32-query sub-tile per block,
// 4096 blocks (R10/R11 multi-sub-tile variants thrash L2). Unchanged.
__global__ __launch_bounds__(256, 4) void attn_kernel(const u16* __restrict__ qkv, const u16* __restrict__ vT,
                                                      const float* __restrict__ biasT,
                                                      float* __restrict__ out) {
  __shared__ u16 p_lds[32 * 512];            // 32 KB
  __shared__ float bias_lds[544];
  __shared__ float reds[4][32];

  const int flat = blockIdx.x;
  const int bh = ((flat >> 7) << 3) | (flat & 7);
  const int q0 = ((flat >> 3) & 15) * 32;
  const int b = bh >> 3, h = bh & 7;
  const int t = threadIdx.x, l = t & 63, w = t >> 6;
  const int lr = l & 15, lq = l >> 4;

  // bias slice (coalesced): bias for (q,key) = bias_lds[key + 31 - (q - q0)]
  {
    const int rel0 = 480 - q0;
    const float* bsrc = biasT + h * 1024 + rel0;
    for (int i = t; i < 543; i += 256)
      bias_lds[i] = bsrc[i];
  }
  // drain the bias-fill global loads so the counted K/V rings below see only
  // their own vmcnt traffic ("memory" also fences compiler load motion).
  asm volatile("s_waitcnt vmcnt(0)" ::: "memory");

  // Q B-frags (pre-scaled by SCALE2 via cvt_w); compiler-managed loads -- any
  // compiler-inserted wait before their first use is conservative vs the ring.
  bf16x8 bq[2][2];
#pragma unroll
  for (int qt = 0; qt < 2; ++qt) {
    const u16* qrow = qkv + (size_t)(b * 512 + q0 + qt * 16 + lr) * NQKV + h * 64;
    bq[qt][0] = *(const bf16x8*)(qrow + lq * 8);
    bq[qt][1] = *(const bf16x8*)(qrow + 32 + lq * 8);
  }

  // ---- phase 1: S^T = K Q^T (already exp2-domain), depth-4 K ring ----
  const u16* kbase = qkv + (size_t)(b * 512 + w * 128 + lr) * NQKV + 512 + h * 64 + lq * 8;
  u32x4 akr[4][2];
  f32x4 sT[2][8];

#define KISSUE(slot, ct) { const u16* kr = kbase + (size_t)(ct) * 16 * NQKV;   \
    asm volatile("global_load_dwordx4 %0, %2, off\n\t"                         \
                 "global_load_dwordx4 %1, %2, off offset:64"                   \
                 : "=&v"(akr[slot][0]), "=&v"(akr[slot][1]) : "v"(kr)); }
  // wait literal = 2 * (pairs issued after pair ct); tied outputs give the
  // MFMAs a data-dep through the wait (no sched_barrier needed, rule #18).
#define KSTEP(ct, lit, doissue) {                                              \
    if (doissue) KISSUE(((ct) + 3) & 3, (ct) + 3)                              \
    asm volatile("s_waitcnt vmcnt(" lit ")"                                    \
                 : "+v"(akr[(ct) & 3][0]), "+v"(akr[(ct) & 3][1]));            \
    bf16x8 ak0 = __builtin_bit_cast(bf16x8, akr[(ct) & 3][0]);                 \
    bf16x8 ak1 = __builtin_bit_cast(bf16x8, akr[(ct) & 3][1]);                 \
    f32x4 a0 = {0.f, 0.f, 0.f, 0.f}, a1 = {0.f, 0.f, 0.f, 0.f};                \
    a0 = __builtin_amdgcn_mfma_f32_16x16x32_bf16(ak0, bq[0][0], a0, 0, 0, 0);  \
    a0 = __builtin_amdgcn_mfma_f32_16x16x32_bf16(ak1, bq[0][1], a0, 0, 0, 0);  \
    a1 = __builtin_amdgcn_mfma_f32_16x16x32_bf16(ak0, bq[1][0], a1, 0, 0, 0);  \
    a1 = __builtin_amdgcn_mfma_f32_16x16x32_bf16(ak1, bq[1][1], a1, 0, 0, 0);  \
    sT[0][ct] = a0; sT[1][ct] = a1; }

  KISSUE(0, 0) KISSUE(1, 1) KISSUE(2, 2)
  KSTEP(0, "6", 1) KSTEP(1, "6", 1) KSTEP(2, "6", 1) KSTEP(3, "6", 1)
  KSTEP(4, "6", 1) KSTEP(5, "4", 0) KSTEP(6, "2", 0) KSTEP(7, "0", 0)
#undef KSTEP
#undef KISSUE

  // exp2 (raw v_exp_f32) + per-query sum; 4 partial accumulators per qt.
  float sq[2];
#pragma unroll
  for (int qt = 0; qt < 2; ++qt) {
    float s0 = 0.f, s1 = 0.f, s2 = 0.f, s3 = 0.f;
#pragma unroll
    for (int ct = 0; ct < 8; ++ct) {
      float e0 = EXP2(sT[qt][ct][0]);
      float e1 = EXP2(sT[qt][ct][1]);
      float e2 = EXP2(sT[qt][ct][2]);
      float e3 = EXP2(sT[qt][ct][3]);
      sT[qt][ct][0] = e0; sT[qt][ct][1] = e1;
      sT[qt][ct][2] = e2; sT[qt][ct][3] = e3;
      s0 += e0; s1 += e1; s2 += e2; s3 += e3;
    }
    sq[qt] = (s0 + s1) + (s2 + s3);
  }
  {
    float t0 = sq[0], t1 = sq[1];
    float u0 = __shfl_xor(t0, 16, 64), u1 = __shfl_xor(t1, 16, 64);
    t0 += u0; t1 += u1;
    u0 = __shfl_xor(t0, 32, 64); u1 = __shfl_xor(t1, 32, 64);
    sq[0] = t0 + u0; sq[1] = t1 + u1;
  }
  if (lq == 0) { reds[w][lr] = sq[0]; reds[w][16 + lr] = sq[1]; }

  // barrier 1: lgkm-only raw barrier (no global traffic to protect here).
  asm volatile("s_waitcnt lgkmcnt(0)" ::: "memory");
  __builtin_amdgcn_s_barrier();
  asm volatile("" ::: "memory");

  float rinv[2];
#pragma unroll
  for (int qt = 0; qt < 2; ++qt)
    rinv[qt] = RCP(reds[0][qt * 16 + lr] + reds[1][qt * 16 + lr] +
                   reds[2][qt * 16 + lr] + reds[3][qt * 16 + lr]);

  // ---- V ring: 8 slots (32 regs) issued BEFORE the pack; they stay in
  // flight across the raw barrier (no vmcnt drain) and land during phase 3.
  const u16* vrow = vT + (size_t)(bh * 64 + w * 16 + lr) * 512 + lq * 8;
  u32x4 avr[8];
#define VISSUE(slot, olit)                                                     \
  asm volatile("global_load_dwordx4 %0, %1, off offset:" olit                  \
               : "=&v"(avr[slot]) : "v"(vrow));
  VISSUE(0, "0")   VISSUE(1, "64")  VISSUE(2, "128") VISSUE(3, "192")
  VISSUE(4, "256") VISSUE(5, "320") VISSUE(6, "384") VISSUE(7, "448")

  // ---- pack P = e*rinv + bias -> bf16 LDS (swizzled b64 stores) ----
#define PACK_QT(qt)                                                            \
  {                                                                            \
    const int qlocal = (qt) * 16 + lr;                                         \
    u16* prow = p_lds + qlocal * 512;                                          \
    const int boff = w * 128 + lq * 4 + 31 - qlocal;                           \
    _Pragma("unroll")                                                          \
    for (int ct = 0; ct < 8; ++ct) {                                           \
      const int gsw = w * 8 + (ct ^ (lr & 7));                                 \
      float p0 = sT[qt][ct][0] * rinv[qt] + bias_lds[boff + ct * 16 + 0];      \
      float p1 = sT[qt][ct][1] * rinv[qt] + bias_lds[boff + ct * 16 + 1];      \
      float p2 = sT[qt][ct][2] * rinv[qt] + bias_lds[boff + ct * 16 + 2];      \
      float p3 = sT[qt][ct][3] * rinv[qt] + bias_lds[boff + ct * 16 + 3];      \
      uint2 pk; pk.x = pack2(p0, p1); pk.y = pack2(p2, p3);                    \
      *(uint2*)&prow[gsw * 16 + lq * 4] = pk;                                  \
    }                                                                          \
  }
  PACK_QT(0)
  PACK_QT(1)
#undef PACK_QT

  // barrier 2: lgkm-only raw barrier -- p_lds writes drained, V loads NOT.
  asm volatile("s_waitcnt lgkmcnt(0)" ::: "memory");
  __builtin_amdgcn_s_barrier();
  asm volatile("" ::: "memory");

  // ---- phase 3 (transposed): out^T(d,q) = V^T(d,k) P^T(k,q) ----
  // V ring continues: consume slot kb&7, issue key kb+8 into the same slot.
  // bp depth-2 pipeline on the LDS P reads (compiler-managed lgkmcnt).
  f32x4 accP[2] = {};
  bf16x8 bp[2][2];
#define LDP(kb, qt) \
  (*(const bf16x8*)&p_lds[((qt) * 16 + lr) * 512 + \
    (((2 * (kb) + (lq >> 1)) & ~7) | (((2 * (kb) + (lq >> 1)) & 7) ^ (lr & 7))) * 16 + (lq & 1) * 8])
  bp[0][0] = LDP(0, 0);
  bp[0][1] = LDP(0, 1);
#define PVSTEP(kb, lit, doissue, olit) {                                       \
    asm volatile("s_waitcnt vmcnt(" lit ")" : "+v"(avr[(kb) & 7]));            \
    if ((kb) < 15) {                                                           \
      bp[((kb) + 1) & 1][0] = LDP((kb) + 1, 0);                                \
      bp[((kb) + 1) & 1][1] = LDP((kb) + 1, 1);                                \
    }                                                                          \
    bf16x8 av = __builtin_bit_cast(bf16x8, avr[(kb) & 7]);                     \
    accP[0] = __builtin_amdgcn_mfma_f32_16x16x32_bf16(av, bp[(kb) & 1][0], accP[0], 0, 0, 0); \
    accP[1] = __builtin_amdgcn_mfma_f32_16x16x32_bf16(av, bp[(kb) & 1][1], accP[1], 0, 0, 0); \
    if (doissue) VISSUE((kb) & 7, olit) }
  PVSTEP(0,  "7", 1, "512") PVSTEP(1,  "7", 1, "576")
  PVSTEP(2,  "7", 1, "640") PVSTEP(3,  "7", 1, "704")
  PVSTEP(4,  "7", 1, "768") PVSTEP(5,  "7", 1, "832")
  PVSTEP(6,  "7", 1, "896") PVSTEP(7,  "7", 1, "960")
  PVSTEP(8,  "7", 0, "0")   PVSTEP(9,  "6", 0, "0")
  PVSTEP(10, "5", 0, "0")   PVSTEP(11, "4", 0, "0")
  PVSTEP(12, "3", 0, "0")   PVSTEP(13, "2", 0, "0")
  PVSTEP(14, "1", 0, "0")   PVSTEP(15, "0", 0, "0")
#undef PVSTEP
#undef VISSUE
#undef LDP
  // D[m=d_off][n=q]: lane holds q = lr, d = w*16 + lq*4 + i  -> f32x4 store
#pragma unroll
  for (int qt = 0; qt < 2; ++qt)
    *(f32x4*)&out[(size_t)(b * 512 + q0 + qt * 16 + lr) * 512 + h * 64 + w * 16 + lq * 4] = accP[qt];
}

// ---------------- LayerNorm: 2 rows/block, float4 ----------------
__global__ __launch_bounds__(256) void ln_kernel(float* __restrict__ out,
                                                 const float* __restrict__ gamma,
                                                 const float* __restrict__ beta) {
  const int t = threadIdx.x;
  const int r2 = t >> 7;                       // row half: 0/1
  const int row = blockIdx.x * 2 + r2;
  const int c = (t & 127) * 4;
  float* p = out + (size_t)row * 512;
  float4 v = *(float4*)(p + c);
  float s = v.x + v.y + v.z + v.w;
  float s2 = v.x * v.x + v.y * v.y + v.z * v.z + v.w * v.w;
#pragma unroll
  for (int d = 1; d < 64; d <<= 1) { s += __shfl_xor(s, d, 64); s2 += __shfl_xor(s2, d, 64); }
  __shared__ float ps[4], ps2[4];
  const int wv = t >> 6;
  if ((t & 63) == 0) { ps[wv] = s; ps2[wv] = s2; }
  __syncthreads();
  s  = ps[r2 * 2]  + ps[r2 * 2 + 1];
  s2 = ps2[r2 * 2] + ps2[r2 * 2 + 1];
  float mu = s * (1.0f / 512.0f);
  float var = s2 * (1.0f / 512.0f) - mu * mu;
  float rs = rsqrtf(var + 1e-5f);
  float4 g = *(const float4*)(gamma + c);
  float4 bb = *(const float4*)(beta + c);
  v.x = g.x * (v.x - mu) * rs + bb.x;
  v.y = g.y * (v.y - mu) * rs + bb.y;
  v.z = g.z * (v.z - mu) * rs + bb.z;
  v.w = g.w * (v.w - mu) * rs + bb.w;
  *(float4*)(p + c) = v;
}

extern "C" void kernel_launch(void* const* d_in, const int* in_sizes, int n_in,
                              void* d_out, int out_size, void* d_ws, size_t ws_size,
                              hipStream_t stream) {
  const float* x    = (const float*)d_in[0];
  const float* wq   = (const float*)d_in[1];
  const float* wk   = (const float*)d_in[2];
  const float* wv   = (const float*)d_in[3];
  const float* bias = (const float*)d_in[4];
  const float* gamma = (const float*)d_in[5];
  const float* beta  = (const float*)d_in[6];
  float* out = (float*)d_out;

  char* ws = (char*)d_ws;
  u16* xb   = (u16*)ws;                       // x in bf16 (reused as vT afterwards)
  u16* wcat = (u16*)(ws + XB_BYTES);          // concat weights bf16 (wq pre-scaled)
  u16* qkv  = (u16*)(ws + QKV_OFF);           // MROWS x 1536 bf16
  u16* vT   = xb;                             // reuse: gemm done with xb before transpose
  float* biasT = (float*)(ws + XB_BYTES);     // reuse wcat region after gemm (8 x 1024 f32)

  cvt_x<<<dim3((MROWS * CC) / 4 / 256), 256, 0, stream>>>(x, xb);
  cvt_w<<<dim3((NQKV * CC) / 4 / 256), 256, 0, stream>>>(wq, wk, wv, wcat);
  gemm_qkv<<<dim3(NQKV / 128, MROWS / 128), 256, 0, stream>>>(xb, wcat, qkv);
  transpose_v<<<dim3(256, 5), 256, 0, stream>>>(qkv, vT, bias, biasT);
  attn_kernel<<<dim3(16 * 256), 256, 0, stream>>>(qkv, vT, biasT, out);
  ln_kernel<<<dim3(MROWS / 2), 256, 0, stream>>>(out, gamma, beta);
}

// Round 10
// 222.035 us; speedup vs baseline: 1.0863x; 1.0208x over previous
//
#include <hip/hip_runtime.h>
#include <hip/hip_bf16.h>

typedef unsigned short u16;
typedef __attribute__((ext_vector_type(8))) __bf16 bf16x8;
typedef __attribute__((ext_vector_type(4))) float f32x4;
typedef __attribute__((ext_vector_type(4))) unsigned int u32x4;

// Problem dims
#define BB 32
#define LL 512
#define CC 512
#define HH 8
#define DH 64
#define MROWS (BB * LL)        // 16384
#define NQKV  (3 * CC)         // 1536

// workspace layout (bytes)
#define XB_BYTES ((size_t)MROWS * CC * 2)        // 16,777,216  (x bf16; later reused as vT)
#define WC_BYTES ((size_t)NQKV * CC * 2)         //  1,572,864  (wq|wk|wv bf16; dead after gemm -> biasT)
#define QKV_OFF  (XB_BYTES + WC_BYTES)           // qkv bf16: MROWS x 1536

// softmax scale (512^-0.5) * log2(e), folded into wq at cvt time: QK^T MFMA
// output is already in the exp2 domain. No max-subtract needed (scores' std
// ~0.07, validated R4).
#define SCALE2 (0.044194173824159216f * 1.4426950408889634f)

#if __has_builtin(__builtin_amdgcn_exp2f)
#define EXP2(x) __builtin_amdgcn_exp2f(x)
#else
#define EXP2(x) exp2f(x)
#endif
#if __has_builtin(__builtin_amdgcn_rcpf)
#define RCP(x) __builtin_amdgcn_rcpf(x)
#else
#define RCP(x) (1.0f / (x))
#endif

__device__ inline u16 f2b(float f) {
  union { float f; unsigned u; } a; a.f = f;
  unsigned u = a.u;
  return (u16)((u + 0x7FFFu + ((u >> 16) & 1u)) >> 16);
}

__device__ inline unsigned pack2(float a, float b) {  // v_cvt_pk_bf16_f32
  float2 f; f.x = a; f.y = b;
  union { __hip_bfloat162 h; unsigned u; } c;
  c.h = __float22bfloat162_rn(f);
  return c.u;
}

// ---------------- fused prep: cvt_x | cvt_w | bias transpose ----------------
// R14: three independent elementwise kernels fused into one launch (saves ~2
// inter-kernel gaps). Branch by blockIdx range; bodies unchanged.
#define CVT_X_BLOCKS ((MROWS * CC) / 4 / 256)    // 8192
#define CVT_W_BLOCKS ((NQKV * CC) / 4 / 256)     // 768
__global__ __launch_bounds__(256) void prep_kernel(const float* __restrict__ x, u16* __restrict__ xb,
                                                   const float* __restrict__ wq, const float* __restrict__ wk,
                                                   const float* __restrict__ wv, u16* __restrict__ wcat,
                                                   const float* __restrict__ bias_table,
                                                   float* __restrict__ biasT) {
  int bid = blockIdx.x;
  const int t = threadIdx.x;
  if (bid < CVT_X_BLOCKS) {                      // ---- cvt_x ----
    int i = bid * 256 + t;                       // one float4 per thread
    float4 v = ((const float4*)x)[i];
    uint2 o; o.x = pack2(v.x, v.y); o.y = pack2(v.z, v.w);
    ((uint2*)xb)[i] = o;
    return;
  }
  bid -= CVT_X_BLOCKS;
  if (bid < CVT_W_BLOCKS) {                      // ---- cvt_w ----
    int i = bid * 256 + t;
    int e = i * 4;
    int n = e >> 9;                              // output row 0..1535
    int k = e & 511;
    const float* src = (n < 512) ? (wq + (size_t)n * 512)
                     : (n < 1024) ? (wk + (size_t)(n - 512) * 512)
                                  : (wv + (size_t)(n - 1024) * 512);
    const float sc = (n < 512) ? SCALE2 : 1.0f;  // fold softmax scale into Q
    float4 v = *(const float4*)(src + k);
    uint2 o; o.x = pack2(v.x * sc, v.y * sc); o.y = pack2(v.z * sc, v.w * sc);
    *(uint2*)(wcat + (size_t)n * 512 + k) = o;
    return;
  }
  bid -= CVT_W_BLOCKS;                           // ---- bias transpose ----
  int i = bid * 256 + t;                         // coalesced read of 1023*8
  if (i < 1023 * 8) {
    float v = bias_table[i];
    int rel = i >> 3, hh = i & 7;
    biasT[hh * 1024 + rel] = v;
  }
}

// ---------------- async global->LDS ----------------
typedef __attribute__((address_space(1))) void* as1_void_p;
typedef __attribute__((address_space(3))) void* as3_void_p;

__device__ inline void async16(const u16* g, u16* l) {
#if __has_builtin(__builtin_amdgcn_global_load_lds)
  __builtin_amdgcn_global_load_lds((as1_void_p)g, (as3_void_p)l, 16, 0, 0);
#else
  *(uint4*)l = *(const uint4*)g;
#endif
}

// ---------------- QKV projection GEMM (R14: 2-phase double-buffer) ---------
// R5-exact K-loop/epilogue (the best-total build) + T3-catalog "minimum
// 2-phase": STAGE(next tile) issued BEFORE compute(current), one
// vmcnt(0)+barrier per K-step. Loads get the full compute phase (~16 MFMAs)
// to land, so the end-of-step drain is cheap. Double buffer at BK=32 costs
// 32 KB LDS total -> 5 blocks/CU preserved (m132's 64KB occupancy cliff
// avoided). Measured catalog delta for this move: ~1.10x (m248v2).
__global__ __launch_bounds__(256) void gemm_qkv(const u16* __restrict__ A, const u16* __restrict__ Bw,
                                                u16* __restrict__ Cm) {
  __shared__ u16 a_lds[2][128 * 32];   // 2 x 8 KB
  __shared__ u16 b_lds[2][128 * 32];   // 2 x 8 KB
  const int n0 = blockIdx.x * 128, m0 = blockIdx.y * 128;
  const int t = threadIdx.x, l = t & 63;
  const int wrow = ((t >> 7) & 1) * 64, wcol = ((t >> 6) & 1) * 64;
  const int lr = l & 15, lq = l >> 4;
  const int c0 = t, c1 = t + 256;
  const int r0 = c0 >> 2, o0 = (c0 & 3) * 8;
  const int r1 = c1 >> 2, o1 = (c1 & 3) * 8;

  f32x4 acc[4][4] = {};

#define STAGE(buf, k0) {                                                       \
    async16(A  + (size_t)(m0 + r0) * 512 + (k0) + o0, &a_lds[buf][c0 * 8]);    \
    async16(A  + (size_t)(m0 + r1) * 512 + (k0) + o1, &a_lds[buf][c1 * 8]);    \
    async16(Bw + (size_t)(n0 + r0) * 512 + (k0) + o0, &b_lds[buf][c0 * 8]);    \
    async16(Bw + (size_t)(n0 + r1) * 512 + (k0) + o1, &b_lds[buf][c1 * 8]);    \
  }

  // prologue: stage tile 0, drain, barrier
  STAGE(0, 0)
  asm volatile("s_waitcnt vmcnt(0)" ::: "memory");
  __syncthreads();

  int buf = 0;
  for (int k0 = 0; k0 < 512; k0 += 32) {
    if (k0 < 480) STAGE(buf ^ 1, k0 + 32)        // issue next tile FIRST
    bf16x8 af[4], bfr[4];
#pragma unroll
    for (int r = 0; r < 4; ++r) af[r]  = *(const bf16x8*)&a_lds[buf][(wrow + r * 16 + lr) * 32 + lq * 8];
#pragma unroll
    for (int c = 0; c < 4; ++c) bfr[c] = *(const bf16x8*)&b_lds[buf][(wcol + c * 16 + lr) * 32 + lq * 8];
#pragma unroll
    for (int r = 0; r < 4; ++r)
#pragma unroll
      for (int c = 0; c < 4; ++c)
        acc[r][c] = __builtin_amdgcn_mfma_f32_16x16x32_bf16(af[r], bfr[c], acc[r][c], 0, 0, 0);
    // next tile complete + all waves done reading this buffer
    asm volatile("s_waitcnt vmcnt(0)" ::: "memory");
    __syncthreads();
    buf ^= 1;
  }
#undef STAGE
#pragma unroll
  for (int r = 0; r < 4; ++r) {
#pragma unroll
    for (int i = 0; i < 4; ++i) {
      int m = m0 + wrow + r * 16 + lq * 4 + i;
      u16* crow = Cm + (size_t)m * NQKV + n0 + wcol;
#pragma unroll
      for (int c = 0; c < 4; ++c)
        crow[c * 16 + lr] = f2b(acc[r][c][i]);
    }
  }
}

// ---------------- V transpose: qkv V-part (b,l,h,d) -> vT[(b*8+h)*64+d][l] --
__global__ __launch_bounds__(256) void transpose_v(const u16* __restrict__ qkv, u16* __restrict__ vT) {
  const int bh = blockIdx.x;
  const int b = bh >> 3, h = bh & 7;
  const int lc0 = blockIdx.y * 128;
  __shared__ u16 tile[32 * 72];
  const int t = threadIdx.x;
  for (int lc = lc0; lc < lc0 + 128; lc += 32) {
    int lrow = t >> 3, dcol = (t & 7) * 8;
    const u16* src = qkv + (size_t)(b * 512 + lc + lrow) * NQKV + 1024 + h * 64 + dcol;
    *(uint4*)&tile[lrow * 72 + dcol] = *(const uint4*)src;
    __syncthreads();
    int d = t >> 2, lp = (t & 3) * 8;
    union { ushort4 v4[2]; u16 s[8]; } tmp;
#pragma unroll
    for (int j = 0; j < 8; ++j) tmp.s[j] = tile[(lp + j) * 72 + d];
    *(uint4*)&vT[(size_t)(bh * 64 + d) * 512 + lc + lp] = *(uint4*)&tmp;
    __syncthreads();
  }
}

// ---------------- fused attention (= exact R9: occupancy-first, rings) ------
// Verified optimum of this structure family: one 32-query sub-tile per block,
// 4096 blocks (R10/R11 multi-sub-tile variants thrash L2; 5 structural
// variants all land 76-78 us). Unchanged.
__global__ __launch_bounds__(256, 4) void attn_kernel(const u16* __restrict__ qkv, const u16* __restrict__ vT,
                                                      const float* __restrict__ biasT,
                                                      float* __restrict__ out) {
  __shared__ u16 p_lds[32 * 512];            // 32 KB
  __shared__ float bias_lds[544];
  __shared__ float reds[4][32];

  const int flat = blockIdx.x;
  const int bh = ((flat >> 7) << 3) | (flat & 7);
  const int q0 = ((flat >> 3) & 15) * 32;
  const int b = bh >> 3, h = bh & 7;
  const int t = threadIdx.x, l = t & 63, w = t >> 6;
  const int lr = l & 15, lq = l >> 4;

  // bias slice (coalesced): bias for (q,key) = bias_lds[key + 31 - (q - q0)]
  {
    const int rel0 = 480 - q0;
    const float* bsrc = biasT + h * 1024 + rel0;
    for (int i = t; i < 543; i += 256)
      bias_lds[i] = bsrc[i];
  }
  // drain the bias-fill global loads so the counted K/V rings below see only
  // their own vmcnt traffic ("memory" also fences compiler load motion).
  asm volatile("s_waitcnt vmcnt(0)" ::: "memory");

  // Q B-frags (pre-scaled by SCALE2 via cvt_w); compiler-managed loads -- any
  // compiler-inserted wait before their first use is conservative vs the ring.
  bf16x8 bq[2][2];
#pragma unroll
  for (int qt = 0; qt < 2; ++qt) {
    const u16* qrow = qkv + (size_t)(b * 512 + q0 + qt * 16 + lr) * NQKV + h * 64;
    bq[qt][0] = *(const bf16x8*)(qrow + lq * 8);
    bq[qt][1] = *(const bf16x8*)(qrow + 32 + lq * 8);
  }

  // ---- phase 1: S^T = K Q^T (already exp2-domain), depth-4 K ring ----
  const u16* kbase = qkv + (size_t)(b * 512 + w * 128 + lr) * NQKV + 512 + h * 64 + lq * 8;
  u32x4 akr[4][2];
  f32x4 sT[2][8];

#define KISSUE(slot, ct) { const u16* kr = kbase + (size_t)(ct) * 16 * NQKV;   \
    asm volatile("global_load_dwordx4 %0, %2, off\n\t"                         \
                 "global_load_dwordx4 %1, %2, off offset:64"                   \
                 : "=&v"(akr[slot][0]), "=&v"(akr[slot][1]) : "v"(kr)); }
  // wait literal = 2 * (pairs issued after pair ct); tied outputs give the
  // MFMAs a data-dep through the wait (no sched_barrier needed, rule #18).
#define KSTEP(ct, lit, doissue) {                                              \
    if (doissue) KISSUE(((ct) + 3) & 3, (ct) + 3)                              \
    asm volatile("s_waitcnt vmcnt(" lit ")"                                    \
                 : "+v"(akr[(ct) & 3][0]), "+v"(akr[(ct) & 3][1]));            \
    bf16x8 ak0 = __builtin_bit_cast(bf16x8, akr[(ct) & 3][0]);                 \
    bf16x8 ak1 = __builtin_bit_cast(bf16x8, akr[(ct) & 3][1]);                 \
    f32x4 a0 = {0.f, 0.f, 0.f, 0.f}, a1 = {0.f, 0.f, 0.f, 0.f};                \
    a0 = __builtin_amdgcn_mfma_f32_16x16x32_bf16(ak0, bq[0][0], a0, 0, 0, 0);  \
    a0 = __builtin_amdgcn_mfma_f32_16x16x32_bf16(ak1, bq[0][1], a0, 0, 0, 0);  \
    a1 = __builtin_amdgcn_mfma_f32_16x16x32_bf16(ak0, bq[1][0], a1, 0, 0, 0);  \
    a1 = __builtin_amdgcn_mfma_f32_16x16x32_bf16(ak1, bq[1][1], a1, 0, 0, 0);  \
    sT[0][ct] = a0; sT[1][ct] = a1; }

  KISSUE(0, 0) KISSUE(1, 1) KISSUE(2, 2)
  KSTEP(0, "6", 1) KSTEP(1, "6", 1) KSTEP(2, "6", 1) KSTEP(3, "6", 1)
  KSTEP(4, "6", 1) KSTEP(5, "4", 0) KSTEP(6, "2", 0) KSTEP(7, "0", 0)
#undef KSTEP
#undef KISSUE

  // exp2 (raw v_exp_f32) + per-query sum; 4 partial accumulators per qt.
  float sq[2];
#pragma unroll
  for (int qt = 0; qt < 2; ++qt) {
    float s0 = 0.f, s1 = 0.f, s2 = 0.f, s3 = 0.f;
#pragma unroll
    for (int ct = 0; ct < 8; ++ct) {
      float e0 = EXP2(sT[qt][ct][0]);
      float e1 = EXP2(sT[qt][ct][1]);
      float e2 = EXP2(sT[qt][ct][2]);
      float e3 = EXP2(sT[qt][ct][3]);
      sT[qt][ct][0] = e0; sT[qt][ct][1] = e1;
      sT[qt][ct][2] = e2; sT[qt][ct][3] = e3;
      s0 += e0; s1 += e1; s2 += e2; s3 += e3;
    }
    sq[qt] = (s0 + s1) + (s2 + s3);
  }
  {
    float t0 = sq[0], t1 = sq[1];
    float u0 = __shfl_xor(t0, 16, 64), u1 = __shfl_xor(t1, 16, 64);
    t0 += u0; t1 += u1;
    u0 = __shfl_xor(t0, 32, 64); u1 = __shfl_xor(t1, 32, 64);
    sq[0] = t0 + u0; sq[1] = t1 + u1;
  }
  if (lq == 0) { reds[w][lr] = sq[0]; reds[w][16 + lr] = sq[1]; }

  // barrier 1: lgkm-only raw barrier (no global traffic to protect here).
  asm volatile("s_waitcnt lgkmcnt(0)" ::: "memory");
  __builtin_amdgcn_s_barrier();
  asm volatile("" ::: "memory");

  float rinv[2];
#pragma unroll
  for (int qt = 0; qt < 2; ++qt)
    rinv[qt] = RCP(reds[0][qt * 16 + lr] + reds[1][qt * 16 + lr] +
                   reds[2][qt * 16 + lr] + reds[3][qt * 16 + lr]);

  // ---- V ring: 8 slots (32 regs) issued BEFORE the pack; they stay in
  // flight across the raw barrier (no vmcnt drain) and land during phase 3.
  const u16* vrow = vT + (size_t)(bh * 64 + w * 16 + lr) * 512 + lq * 8;
  u32x4 avr[8];
#define VISSUE(slot, olit)                                                     \
  asm volatile("global_load_dwordx4 %0, %1, off offset:" olit                  \
               : "=&v"(avr[slot]) : "v"(vrow));
  VISSUE(0, "0")   VISSUE(1, "64")  VISSUE(2, "128") VISSUE(3, "192")
  VISSUE(4, "256") VISSUE(5, "320") VISSUE(6, "384") VISSUE(7, "448")

  // ---- pack P = e*rinv + bias -> bf16 LDS (swizzled b64 stores) ----
#define PACK_QT(qt)                                                            \
  {                                                                            \
    const int qlocal = (qt) * 16 + lr;                                         \
    u16* prow = p_lds + qlocal * 512;                                          \
    const int boff = w * 128 + lq * 4 + 31 - qlocal;                           \
    _Pragma("unroll")                                                          \
    for (int ct = 0; ct < 8; ++ct) {                                           \
      const int gsw = w * 8 + (ct ^ (lr & 7));                                 \
      float p0 = sT[qt][ct][0] * rinv[qt] + bias_lds[boff + ct * 16 + 0];      \
      float p1 = sT[qt][ct][1] * rinv[qt] + bias_lds[boff + ct * 16 + 1];      \
      float p2 = sT[qt][ct][2] * rinv[qt] + bias_lds[boff + ct * 16 + 2];      \
      float p3 = sT[qt][ct][3] * rinv[qt] + bias_lds[boff + ct * 16 + 3];      \
      uint2 pk; pk.x = pack2(p0, p1); pk.y = pack2(p2, p3);                    \
      *(uint2*)&prow[gsw * 16 + lq * 4] = pk;                                  \
    }                                                                          \
  }
  PACK_QT(0)
  PACK_QT(1)
#undef PACK_QT

  // barrier 2: lgkm-only raw barrier -- p_lds writes drained, V loads NOT.
  asm volatile("s_waitcnt lgkmcnt(0)" ::: "memory");
  __builtin_amdgcn_s_barrier();
  asm volatile("" ::: "memory");

  // ---- phase 3 (transposed): out^T(d,q) = V^T(d,k) P^T(k,q) ----
  // V ring continues: consume slot kb&7, issue key kb+8 into the same slot.
  // bp depth-2 pipeline on the LDS P reads (compiler-managed lgkmcnt).
  f32x4 accP[2] = {};
  bf16x8 bp[2][2];
#define LDP(kb, qt) \
  (*(const bf16x8*)&p_lds[((qt) * 16 + lr) * 512 + \
    (((2 * (kb) + (lq >> 1)) & ~7) | (((2 * (kb) + (lq >> 1)) & 7) ^ (lr & 7))) * 16 + (lq & 1) * 8])
  bp[0][0] = LDP(0, 0);
  bp[0][1] = LDP(0, 1);
#define PVSTEP(kb, lit, doissue, olit) {                                       \
    asm volatile("s_waitcnt vmcnt(" lit ")" : "+v"(avr[(kb) & 7]));            \
    if ((kb) < 15) {                                                           \
      bp[((kb) + 1) & 1][0] = LDP((kb) + 1, 0);                                \
      bp[((kb) + 1) & 1][1] = LDP((kb) + 1, 1);                                \
    }                                                                          \
    bf16x8 av = __builtin_bit_cast(bf16x8, avr[(kb) & 7]);                     \
    accP[0] = __builtin_amdgcn_mfma_f32_16x16x32_bf16(av, bp[(kb) & 1][0], accP[0], 0, 0, 0); \
    accP[1] = __builtin_amdgcn_mfma_f32_16x16x32_bf16(av, bp[(kb) & 1][1], accP[1], 0, 0, 0); \
    if (doissue) VISSUE((kb) & 7, olit) }
  PVSTEP(0,  "7", 1, "512") PVSTEP(1,  "7", 1, "576")
  PVSTEP(2,  "7", 1, "640") PVSTEP(3,  "7", 1, "704")
  PVSTEP(4,  "7", 1, "768") PVSTEP(5,  "7", 1, "832")
  PVSTEP(6,  "7", 1, "896") PVSTEP(7,  "7", 1, "960")
  PVSTEP(8,  "7", 0, "0")   PVSTEP(9,  "6", 0, "0")
  PVSTEP(10, "5", 0, "0")   PVSTEP(11, "4", 0, "0")
  PVSTEP(12, "3", 0, "0")   PVSTEP(13, "2", 0, "0")
  PVSTEP(14, "1", 0, "0")   PVSTEP(15, "0", 0, "0")
#undef PVSTEP
#undef VISSUE
#undef LDP
  // D[m=d_off][n=q]: lane holds q = lr, d = w*16 + lq*4 + i  -> f32x4 store
#pragma unroll
  for (int qt = 0; qt < 2; ++qt)
    *(f32x4*)&out[(size_t)(b * 512 + q0 + qt * 16 + lr) * 512 + h * 64 + w * 16 + lq * 4] = accP[qt];
}

// ---------------- LayerNorm: 2 rows/block, float4 ----------------
__global__ __launch_bounds__(256) void ln_kernel(float* __restrict__ out,
                                                 const float* __restrict__ gamma,
                                                 const float* __restrict__ beta) {
  const int t = threadIdx.x;
  const int r2 = t >> 7;                       // row half: 0/1
  const int row = blockIdx.x * 2 + r2;
  const int c = (t & 127) * 4;
  float* p = out + (size_t)row * 512;
  float4 v = *(float4*)(p + c);
  float s = v.x + v.y + v.z + v.w;
  float s2 = v.x * v.x + v.y * v.y + v.z * v.z + v.w * v.w;
#pragma unroll
  for (int d = 1; d < 64; d <<= 1) { s += __shfl_xor(s, d, 64); s2 += __shfl_xor(s2, d, 64); }
  __shared__ float ps[4], ps2[4];
  const int wv = t >> 6;
  if ((t & 63) == 0) { ps[wv] = s; ps2[wv] = s2; }
  __syncthreads();
  s  = ps[r2 * 2]  + ps[r2 * 2 + 1];
  s2 = ps2[r2 * 2] + ps2[r2 * 2 + 1];
  float mu = s * (1.0f / 512.0f);
  float var = s2 * (1.0f / 512.0f) - mu * mu;
  float rs = rsqrtf(var + 1e-5f);
  float4 g = *(const float4*)(gamma + c);
  float4 bb = *(const float4*)(beta + c);
  v.x = g.x * (v.x - mu) * rs + bb.x;
  v.y = g.y * (v.y - mu) * rs + bb.y;
  v.z = g.z * (v.z - mu) * rs + bb.z;
  v.w = g.w * (v.w - mu) * rs + bb.w;
  *(float4*)(p + c) = v;
}

extern "C" void kernel_launch(void* const* d_in, const int* in_sizes, int n_in,
                              void* d_out, int out_size, void* d_ws, size_t ws_size,
                              hipStream_t stream) {
  const float* x    = (const float*)d_in[0];
  const float* wq   = (const float*)d_in[1];
  const float* wk   = (const float*)d_in[2];
  const float* wv   = (const float*)d_in[3];
  const float* bias = (const float*)d_in[4];
  const float* gamma = (const float*)d_in[5];
  const float* beta  = (const float*)d_in[6];
  float* out = (float*)d_out;

  char* ws = (char*)d_ws;
  u16* xb   = (u16*)ws;                       // x in bf16 (reused as vT afterwards)
  u16* wcat = (u16*)(ws + XB_BYTES);          // concat weights bf16 (wq pre-scaled)
  u16* qkv  = (u16*)(ws + QKV_OFF);           // MROWS x 1536 bf16
  u16* vT   = xb;                             // reuse: gemm done with xb before transpose
  float* biasT = (float*)(ws + XB_BYTES + WC_BYTES - 8 * 1024 * 4);  // tail of wcat region
  // NOTE: biasT must not alias wcat rows still read by gemm -- it is written
  // by prep BEFORE gemm reads wcat. Keep biasT in its own spot: use the same
  // address as before (start of wcat region is read by gemm!). Place biasT
  // after qkv instead to be safe:
  biasT = (float*)(ws + QKV_OFF + (size_t)MROWS * NQKV * 2);

  prep_kernel<<<dim3(CVT_X_BLOCKS + CVT_W_BLOCKS + 32), 256, 0, stream>>>(
      x, xb, wq, wk, wv, wcat, bias, biasT);
  gemm_qkv<<<dim3(NQKV / 128, MROWS / 128), 256, 0, stream>>>(xb, wcat, qkv);
  transpose_v<<<dim3(256, 4), 256, 0, stream>>>(qkv, vT);
  attn_kernel<<<dim3(16 * 256), 256, 0, stream>>>(qkv, vT, biasT, out);
  ln_kernel<<<dim3(MROWS / 2), 256, 0, stream>>>(out, gamma, beta);
}